// Round 1
// baseline (394.924 us; speedup 1.0000x reference)
//
#include <hip/hip_runtime.h>
#include <hip/hip_bf16.h>
#include <stdint.h>

// Problem constants (from setup_inputs): x (8,4096,1024) f32, weight (1024,1024) f32, bias (1024,)
#define NXK 1024   // K = nx
#define NFN 1024   // N = nf
#define EPSQ 0.01f

typedef __bf16 bf16x8 __attribute__((ext_vector_type(8)));
typedef float f32x4 __attribute__((ext_vector_type(4)));

#define AS1(p) ((const __attribute__((address_space(1))) void*)(p))
#define AS3(p) ((__attribute__((address_space(3))) void*)(p))

// smallest power of two >= m, for positive normal m. Matches exp2(ceil(log2(m))).
__device__ __forceinline__ float p2ceil(float m) {
    unsigned u = __float_as_uint(m);
    if ((u & 0x7fffffu) == 0) return m;               // exact power of 2
    return __uint_as_float((((u >> 23) & 0xffu) + 1u) << 23);
}

__device__ __forceinline__ unsigned short f2bf(float f) {
    __bf16 h = (__bf16)f;   // RNE; values are exactly representable anyway
    return __builtin_bit_cast(unsigned short, h);
}

// ---------------------------------------------------------------------------
// Kernel 1: per-column max|X| over rows, via uint-bit atomicMax (|x| >= 0).
// One block covers RPB rows x 1024 cols; thread t owns cols [4t, 4t+4).
// ---------------------------------------------------------------------------
#define RPB 64
__global__ __launch_bounds__(256) void colmax_kernel(const float* __restrict__ X,
                                                     unsigned int* __restrict__ cmax) {
    const int t = threadIdx.x;
    const size_t r0 = (size_t)blockIdx.x * RPB;
    const float4* Xv = (const float4*)X;
    float m0 = 0.f, m1 = 0.f, m2 = 0.f, m3 = 0.f;
#pragma unroll 8
    for (int i = 0; i < RPB; ++i) {
        float4 v = Xv[(r0 + i) * (NXK / 4) + t];
        m0 = fmaxf(m0, fabsf(v.x));
        m1 = fmaxf(m1, fabsf(v.y));
        m2 = fmaxf(m2, fabsf(v.z));
        m3 = fmaxf(m3, fabsf(v.w));
    }
    atomicMax(&cmax[4 * t + 0], __float_as_uint(m0));
    atomicMax(&cmax[4 * t + 1], __float_as_uint(m1));
    atomicMax(&cmax[4 * t + 2], __float_as_uint(m2));
    atomicMax(&cmax[4 * t + 3], __float_as_uint(m3));
}

// ---------------------------------------------------------------------------
// Kernel 2: per-row: scale by s_col, row max -> s_row, quantize, dequantize,
// store bf16. TRANSPOSE=1 stores Q^T (for the weight -> B^T GEMM layout).
// One block per row, 256 threads, thread t owns cols [4t, 4t+4).
// ---------------------------------------------------------------------------
template <int TRANSPOSE>
__global__ __launch_bounds__(256) void rowquant_kernel(const float* __restrict__ X,
                                                       const unsigned int* __restrict__ cmaxbits,
                                                       unsigned short* __restrict__ Q) {
    const int m = blockIdx.x;
    const int t = threadIdx.x;
    const float4 v = ((const float4*)(X + (size_t)m * NXK))[t];
    const uint4 cb = ((const uint4*)cmaxbits)[t];

    const float sc0 = p2ceil(fmaxf(__uint_as_float(cb.x), EPSQ));
    const float sc1 = p2ceil(fmaxf(__uint_as_float(cb.y), EPSQ));
    const float sc2 = p2ceil(fmaxf(__uint_as_float(cb.z), EPSQ));
    const float sc3 = p2ceil(fmaxf(__uint_as_float(cb.w), EPSQ));

    const float r0 = v.x / sc0;   // exact: power-of-2 divide
    const float r1 = v.y / sc1;
    const float r2 = v.z / sc2;
    const float r3 = v.w / sc3;

    float amax = fmaxf(fmaxf(fabsf(r0), fabsf(r1)), fmaxf(fabsf(r2), fabsf(r3)));
#pragma unroll
    for (int s = 32; s >= 1; s >>= 1) amax = fmaxf(amax, __shfl_xor(amax, s, 64));
    __shared__ float wmax[4];
    if ((t & 63) == 0) wmax[t >> 6] = amax;
    __syncthreads();
    amax = fmaxf(fmaxf(wmax[0], wmax[1]), fmaxf(wmax[2], wmax[3]));

    const float srow = p2ceil(fmaxf(amax, EPSQ));
    const float inv = 128.0f / srow;               // exact power of 2
    // q = clip(rint(r * 128 / srow), -128, 127); rintf == round-half-even == jnp.round
    const float q0 = fminf(fmaxf(rintf(r0 * inv), -128.0f), 127.0f);
    const float q1 = fminf(fmaxf(rintf(r1 * inv), -128.0f), 127.0f);
    const float q2 = fminf(fmaxf(rintf(r2 * inv), -128.0f), 127.0f);
    const float q3 = fminf(fmaxf(rintf(r3 * inv), -128.0f), 127.0f);

    const float rs = srow * 0.0078125f;            // srow/128, exact
    // dequant: s_col * q * (s_row/128) — all powers of 2 times small int: exact, bf16-exact
    if (TRANSPOSE) {
        Q[(size_t)(4 * t + 0) * NXK + m] = f2bf(q0 * (sc0 * rs));
        Q[(size_t)(4 * t + 1) * NXK + m] = f2bf(q1 * (sc1 * rs));
        Q[(size_t)(4 * t + 2) * NXK + m] = f2bf(q2 * (sc2 * rs));
        Q[(size_t)(4 * t + 3) * NXK + m] = f2bf(q3 * (sc3 * rs));
    } else {
        ushort4 o;
        o.x = f2bf(q0 * (sc0 * rs));
        o.y = f2bf(q1 * (sc1 * rs));
        o.z = f2bf(q2 * (sc2 * rs));
        o.w = f2bf(q3 * (sc3 * rs));
        ((ushort4*)(Q + (size_t)m * NXK))[t] = o;
    }
}

// ---------------------------------------------------------------------------
// Kernel 3: bf16 GEMM, m97 structure: 128x128 tile, BK=32, 4 waves (2x2),
// 4x4 16x16x32 frags per wave, global_load_lds width-16 staging, 2 barriers.
// A: (M,K) row-major bf16 bits. BT: (N,K) row-major. C: (M,N) f32 + bias.
// ---------------------------------------------------------------------------
__global__ __launch_bounds__(256) void gemm_kernel(const unsigned short* __restrict__ A,
                                                   const unsigned short* __restrict__ BT,
                                                   const float* __restrict__ bias,
                                                   float* __restrict__ C, int M) {
    constexpr int K = NXK, N = NFN;
    __shared__ unsigned short As[128][32];   // 8 KB
    __shared__ unsigned short Bs[128][32];   // 8 KB

    const int tid = threadIdx.x;
    const int wave = tid >> 6, lane = tid & 63;
    const int wr = wave >> 1, wc = wave & 1;
    const int bm = blockIdx.y * 128, bn = blockIdx.x * 128;

    f32x4 acc[4][4] = {};

    // Staging: wave w covers tile rows [w*32, w*32+32), two 1024B insts of 16 rows.
    // LDS dest = wave-uniform base + lane*16B == row (lane>>2), 16B-chunk (lane&3).
    const int strow = wave * 32 + (lane >> 2);
    const int stcol = (lane & 3) * 8;
    const unsigned short* gA = A + (size_t)(bm + strow) * K + stcol;
    const unsigned short* gB = BT + (size_t)(bn + strow) * K + stcol;
    unsigned short* lA0 = &As[wave * 32][0];
    unsigned short* lA1 = &As[wave * 32 + 16][0];
    unsigned short* lB0 = &Bs[wave * 32][0];
    unsigned short* lB1 = &Bs[wave * 32 + 16][0];

    for (int k0 = 0; k0 < K; k0 += 32) {
        __builtin_amdgcn_global_load_lds(AS1(gA + k0),          AS3(lA0), 16, 0, 0);
        __builtin_amdgcn_global_load_lds(AS1(gA + 16 * K + k0), AS3(lA1), 16, 0, 0);
        __builtin_amdgcn_global_load_lds(AS1(gB + k0),          AS3(lB0), 16, 0, 0);
        __builtin_amdgcn_global_load_lds(AS1(gB + 16 * K + k0), AS3(lB1), 16, 0, 0);
        asm volatile("s_waitcnt vmcnt(0)" ::: "memory");
        __syncthreads();

        bf16x8 af[4], bf[4];
#pragma unroll
        for (int i = 0; i < 4; ++i) {
            af[i] = *(const bf16x8*)&As[wr * 64 + i * 16 + (lane & 15)][(lane >> 4) * 8];
            bf[i] = *(const bf16x8*)&Bs[wc * 64 + i * 16 + (lane & 15)][(lane >> 4) * 8];
        }
#pragma unroll
        for (int mi = 0; mi < 4; ++mi)
#pragma unroll
            for (int ni = 0; ni < 4; ++ni)
                acc[mi][ni] = __builtin_amdgcn_mfma_f32_16x16x32_bf16(af[mi], bf[ni], acc[mi][ni], 0, 0, 0);
        __syncthreads();
    }

    // Epilogue: C/D layout col=lane&15, row=(lane>>4)*4+j  [m89-verified]
#pragma unroll
    for (int mi = 0; mi < 4; ++mi) {
#pragma unroll
        for (int ni = 0; ni < 4; ++ni) {
            const int col = bn + wc * 64 + ni * 16 + (lane & 15);
            const float bv = bias[col];
#pragma unroll
            for (int j = 0; j < 4; ++j) {
                const int row = bm + wr * 64 + mi * 16 + (lane >> 4) * 4 + j;
                C[(size_t)row * N + col] = acc[mi][ni][j] + bv;
            }
        }
    }
}

// ---------------------------------------------------------------------------
extern "C" void kernel_launch(void* const* d_in, const int* in_sizes, int n_in,
                              void* d_out, int out_size, void* d_ws, size_t ws_size,
                              hipStream_t stream) {
    const float* x    = (const float*)d_in[0];
    const float* w    = (const float*)d_in[1];
    const float* bias = (const float*)d_in[2];
    float* out = (float*)d_out;
    const int M = in_sizes[0] / NXK;   // 32768

    // workspace layout (needs ~70 MB): xq (M*K bf16) | wqT (N*K bf16) | colmax_x | colmax_w
    char* ws = (char*)d_ws;
    unsigned short* xq = (unsigned short*)ws;
    size_t off = (size_t)M * NXK * sizeof(unsigned short);
    unsigned short* wqT = (unsigned short*)(ws + off);
    off += (size_t)NFN * NXK * sizeof(unsigned short);
    unsigned int* cmx = (unsigned int*)(ws + off);   // NXK entries, then NFN entries
    unsigned int* cmw = cmx + NXK;

    hipMemsetAsync(cmx, 0, (NXK + NFN) * sizeof(unsigned int), stream);

    colmax_kernel<<<M / RPB, 256, 0, stream>>>(x, cmx);
    colmax_kernel<<<NXK / RPB, 256, 0, stream>>>(w, cmw);
    rowquant_kernel<0><<<M, 256, 0, stream>>>(x, cmx, xq);
    rowquant_kernel<1><<<NXK, 256, 0, stream>>>(w, cmw, wqT);
    gemm_kernel<<<dim3(NFN / 128, M / 128), 256, 0, stream>>>(xq, wqT, bias, out, M);
}